// Round 7
// baseline (237.581 us; speedup 1.0000x reference)
//
#include <hip/hip_runtime.h>

// KMeans assignment: costs[i] = min_k ||x_i-c_k||^2, indices[i] = argmin_k.
// argmin over k of (c2[k] - 2*dot(x,c_k)); x2 additive, added at the end.
// Cross term via split-f16 3-pass MFMA (xh.ch + xl.ch + xh.cl), err ~1e-6.
// R7: BARRIER-FREE K-LOOP. B (hi AND lo) fragments go global->register from
// the L2-resident pre-tiled layout, ping-pong parity tied to the statically
// unrolled kc loop (2 sets = 64 VGPR in flight, R5-proven pattern). A is
// read-only in LDS after the prologue. No __syncthreads anywhere in the
// K-loop -> no wave convoys; per-wave MFMA/load interleave w/ fine vmcnt.
// LDS = 64KB A + 2KB reduce -> 2 blocks/CU.
// N=131072, D=128, K=1024.  d_out = [costs (N f32), indices-as-f32 (N)].

typedef _Float16 f16x8 __attribute__((ext_vector_type(8)));
typedef float    f32x4 __attribute__((ext_vector_type(4)));
typedef unsigned short u16;

constexpr int N = 131072, D = 128, K = 1024;
constexpr int MT = 128;   // points per block

union H2U { _Float16 h; unsigned short u; };

// ---- prep: centers -> hi/lo f16 in fragment-major tiled layout + exact c2 ----
// ushort idx: (((cb*4 + kc)*4 + q)*128 + c%128)*8 + j, k = kc*32 + q*8 + j
__global__ void prep_centers(const float* __restrict__ centers,
                             u16* __restrict__ Bh, u16* __restrict__ Bl,
                             float* __restrict__ c2) {
  const int wave = threadIdx.x >> 6, lane = threadIdx.x & 63;
  const int c = blockIdx.x * 4 + wave;          // one wave per center
  const float2 v = ((const float2*)(centers + (size_t)c * D))[lane];
  float s = v.x * v.x + v.y * v.y;
  #pragma unroll
  for (int off = 32; off; off >>= 1) s += __shfl_xor(s, off, 64);
  if (lane == 0) c2[c] = s;

  H2U h0, h1, l0, l1;
  h0.h = (_Float16)v.x;  l0.h = (_Float16)(v.x - (float)h0.h);
  h1.h = (_Float16)v.y;  l1.h = (_Float16)(v.y - (float)h1.h);
  const int cb = c >> 7, cm = c & 127;
  const int kc = lane >> 4, q = (lane >> 2) & 3, j0 = (lane & 3) * 2;
  const size_t off = (((size_t)(cb * 4 + kc) * 4 + q) * 128 + cm) * 8 + j0;
  *(unsigned*)(Bh + off) = (unsigned)h0.u | ((unsigned)h1.u << 16);
  *(unsigned*)(Bl + off) = (unsigned)l0.u | ((unsigned)l1.u << 16);
}

// ---- main: 128 pts x 1024 centers per block; wave tile 64x64 (2x2 waves) ----
__global__ __launch_bounds__(256, 2) void kmeans_mfma(
    const float* __restrict__ x,
    const u16* __restrict__ Bh_g, const u16* __restrict__ Bl_g,
    const float* __restrict__ c2g,
    float* __restrict__ out_cost, float* __restrict__ out_idx)
{
  __shared__ __align__(16) u16 Ah[16384];   // [kc4][q4][m128][j8]  32 KB
  __shared__ __align__(16) u16 Al[16384];   //                      32 KB
  __shared__ float redV[256];               //                       1 KB
  __shared__ int   redI[256];               //                       1 KB

  const int tid = threadIdx.x;
  const int wave = tid >> 6, lane = tid & 63;
  const int wr = wave >> 1, wc = wave & 1;    // wave row/col in 2x2
  const int q = lane >> 4, ln = lane & 15;
  const int m0 = blockIdx.x * MT;

  // ---- stage A tile: fp32 -> (hi,lo) f16, tiled layout ----
  #pragma unroll
  for (int i = 0; i < 16; ++i) {
    const int flat = i * 256 + tid;            // 4096 float4s = 128x128 floats
    const int m = flat >> 5, c4 = flat & 31, k0 = c4 * 4;
    const float4 v = *(const float4*)(x + (size_t)(m0 + m) * D + k0);
    const int kc = k0 >> 5, qq = (k0 >> 3) & 3, j0 = k0 & 7;
    const float vv[4] = {v.x, v.y, v.z, v.w};
    H2U h[4], l[4];
    #pragma unroll
    for (int z = 0; z < 4; ++z) {
      h[z].h = (_Float16)vv[z];
      l[z].h = (_Float16)(vv[z] - (float)h[z].h);
    }
    const int off = ((kc * 4 + qq) * 128 + m) * 8 + j0;
    uint2 hp, lp;
    hp.x = h[0].u | ((unsigned)h[1].u << 16); hp.y = h[2].u | ((unsigned)h[3].u << 16);
    lp.x = l[0].u | ((unsigned)l[1].u << 16); lp.y = l[2].u | ((unsigned)l[3].u << 16);
    *(uint2*)(Ah + off) = hp;
    *(uint2*)(Al + off) = lp;
  }
  __syncthreads();   // A is READ-ONLY from here on -- last barrier before epilogue

  // ---- x2 per point (thread tid<128 owns m=tid) ----
  float x2m = 0.f;
  if (tid < MT) {
    #pragma unroll
    for (int kq = 0; kq < 16; ++kq) {
      const f16x8 hv = *(const f16x8*)(Ah + (kq * 128 + tid) * 8);
      const f16x8 lv = *(const f16x8*)(Al + (kq * 128 + tid) * 8);
      #pragma unroll
      for (int e = 0; e < 8; ++e) {
        const float xv = (float)hv[e] + (float)lv[e];
        x2m += xv * xv;
      }
    }
  }

  // per-lane base into the fragment-major B arrays (u16 units)
  const size_t laneB = ((size_t)q * 128 + wc * 64 + ln) * 8;
  const u16* bhP = Bh_g + laneB;
  const u16* blP = Bl_g + laneB;

  float bestV[16]; int bestI[16];
  #pragma unroll
  for (int b = 0; b < 16; ++b) { bestV[b] = 3.4e38f; bestI[b] = 0; }

  // B fragment ping-pong: set parity = kc & 1 (statically unrolled kc)
  f16x8 bhS[2][4], blS[2][4];
  #pragma unroll
  for (int t = 0; t < 4; ++t) {          // chunk 0 -> set0
    bhS[0][t] = *(const f16x8*)(bhP + t * 128);
    blS[0][t] = *(const f16x8*)(blP + t * 128);
  }

  for (int ct = 0; ct < 8; ++ct) {
    f32x4 acc[4][4];
    #pragma unroll
    for (int mt = 0; mt < 4; ++mt)
      #pragma unroll
      for (int nt = 0; nt < 4; ++nt)
        acc[mt][nt] = (f32x4){0.f, 0.f, 0.f, 0.f};

    // c2 for this ct tile (L2 hit, consumed ~a full tile-compute later)
    float c2v[4];
    #pragma unroll
    for (int nt = 0; nt < 4; ++nt)
      c2v[nt] = c2g[ct * 128 + wc * 64 + nt * 16 + ln];

    #pragma unroll
    for (int kc = 0; kc < 4; ++kc) {
      const int cc = ct * 4 + kc;
      const int cur = kc & 1, nxt = cur ^ 1;

      // prefetch chunk cc+1 into the other set (kc<3 folds at compile time)
      if (kc < 3 || ct < 7) {
        const size_t goff = (size_t)(cc + 1) * 4096;
        #pragma unroll
        for (int t = 0; t < 4; ++t) {
          bhS[nxt][t] = *(const f16x8*)(bhP + goff + t * 128);
          blS[nxt][t] = *(const f16x8*)(blP + goff + t * 128);
        }
      }

      // A fragments for chunk cc from (read-only) LDS
      f16x8 ah[4], al[4];
      #pragma unroll
      for (int t = 0; t < 4; ++t) {
        const int aoff = ((kc * 4 + q) * 128 + wr * 64 + t * 16 + ln) * 8;
        ah[t] = *(const f16x8*)(Ah + aoff);
        al[t] = *(const f16x8*)(Al + aoff);
      }

      // 3-pass split-f16: 48 MFMA per chunk (same order as R2 -> bit-identical)
      #pragma unroll
      for (int mt = 0; mt < 4; ++mt)
        #pragma unroll
        for (int nt = 0; nt < 4; ++nt)
          acc[mt][nt] = __builtin_amdgcn_mfma_f32_16x16x32_f16(ah[mt], bhS[cur][nt], acc[mt][nt], 0, 0, 0);
      #pragma unroll
      for (int mt = 0; mt < 4; ++mt)
        #pragma unroll
        for (int nt = 0; nt < 4; ++nt)
          acc[mt][nt] = __builtin_amdgcn_mfma_f32_16x16x32_f16(al[mt], bhS[cur][nt], acc[mt][nt], 0, 0, 0);
      #pragma unroll
      for (int mt = 0; mt < 4; ++mt)
        #pragma unroll
        for (int nt = 0; nt < 4; ++nt)
          acc[mt][nt] = __builtin_amdgcn_mfma_f32_16x16x32_f16(ah[mt], blS[cur][nt], acc[mt][nt], 0, 0, 0);
    }

    // epilogue: s = c2 - 2*dot; running min (n strictly increasing per lane)
    #pragma unroll
    for (int nt = 0; nt < 4; ++nt) {
      const int n = ct * 128 + wc * 64 + nt * 16 + ln;
      #pragma unroll
      for (int mt = 0; mt < 4; ++mt)
        #pragma unroll
        for (int r = 0; r < 4; ++r) {
          const float s = __builtin_fmaf(-2.f, acc[mt][nt][r], c2v[nt]);
          const int b = mt * 4 + r;
          if (s < bestV[b]) { bestV[b] = s; bestI[b] = n; }
        }
    }
  }

  // ---- reduce across the 16 lanes (ln) sharing the same m rows ----
  #pragma unroll
  for (int b = 0; b < 16; ++b) {
    float v = bestV[b]; int idx = bestI[b];
    #pragma unroll
    for (int off = 1; off < 16; off <<= 1) {
      const float ov = __shfl_xor(v, off, 64);
      const int   oi = __shfl_xor(idx, off, 64);
      if (ov < v || (ov == v && oi < idx)) { v = ov; idx = oi; }
    }
    bestV[b] = v; bestI[b] = idx;
  }

  if (ln == 0) {
    #pragma unroll
    for (int b = 0; b < 16; ++b) {
      const int ml = wr * 64 + (b >> 2) * 16 + q * 4 + (b & 3);
      redV[ml * 2 + wc] = bestV[b];
      redI[ml * 2 + wc] = bestI[b];
    }
  }
  __syncthreads();
  if (tid < MT) {
    float v = redV[tid * 2]; int idx = redI[tid * 2];
    const float v1 = redV[tid * 2 + 1]; const int i1 = redI[tid * 2 + 1];
    if (v1 < v || (v1 == v && i1 < idx)) { v = v1; idx = i1; }
    float cost = x2m + v;
    if (cost < 0.f) cost = 0.f;          // clamp like reference
    out_cost[m0 + tid] = cost;
    out_idx[m0 + tid]  = (float)idx;
  }
}

extern "C" void kernel_launch(void* const* d_in, const int* in_sizes, int n_in,
                              void* d_out, int out_size, void* d_ws, size_t ws_size,
                              hipStream_t stream) {
  const float* x       = (const float*)d_in[0];
  const float* centers = (const float*)d_in[1];
  u16*   Bh = (u16*)d_ws;                    // 256 KB
  u16*   Bl = Bh + (size_t)K * D;            // 256 KB
  float* c2 = (float*)(Bl + (size_t)K * D);  // 4 KB
  float* out_cost = (float*)d_out;
  float* out_idx  = out_cost + N;

  prep_centers<<<K / 4, 256, 0, stream>>>(centers, Bh, Bl, c2);
  kmeans_mfma<<<N / MT, 256, 0, stream>>>(x, Bh, Bl, c2, out_cost, out_idx);
}

// Round 8
// 220.478 us; speedup vs baseline: 1.0776x; 1.0776x over previous
//
#include <hip/hip_runtime.h>

// KMeans assignment: costs[i] = min_k ||x_i-c_k||^2, indices[i] = argmin_k.
// argmin over k of (c2[k] - 2*dot(x,c_k)); x2 additive, added at the end.
// Cross term via split-f16 3-pass MFMA (xh.ch + xl.ch + xh.cl), err ~1e-6.
// R8 = R7 barrier-free K-loop + amdgpu_waves_per_eu(2,2) to FORCE the
// 256-reg/lane budget (launch_bounds(256,2) alone leaves RA at 128 + spill,
// proven R3/R4/R7 by WRITE_SIZE blowups). In-flight B trimmed to 48 regs:
// bh double-set ping-pong (32) + just-in-time bl (16, consumed only in
// pass 3 so its L2 latency hides under passes 1-2). A read-only in LDS.
// No __syncthreads in the K-loop -> no wave convoys.
// LDS = 64KB A + 2KB reduce -> 2 blocks/CU (the occupancy we force).
// N=131072, D=128, K=1024.  d_out = [costs (N f32), indices-as-f32 (N)].

typedef _Float16 f16x8 __attribute__((ext_vector_type(8)));
typedef float    f32x4 __attribute__((ext_vector_type(4)));
typedef unsigned short u16;

constexpr int N = 131072, D = 128, K = 1024;
constexpr int MT = 128;   // points per block

union H2U { _Float16 h; unsigned short u; };

// ---- prep: centers -> hi/lo f16 in fragment-major tiled layout + exact c2 ----
// ushort idx: (((cb*4 + kc)*4 + q)*128 + c%128)*8 + j, k = kc*32 + q*8 + j
__global__ void prep_centers(const float* __restrict__ centers,
                             u16* __restrict__ Bh, u16* __restrict__ Bl,
                             float* __restrict__ c2) {
  const int wave = threadIdx.x >> 6, lane = threadIdx.x & 63;
  const int c = blockIdx.x * 4 + wave;          // one wave per center
  const float2 v = ((const float2*)(centers + (size_t)c * D))[lane];
  float s = v.x * v.x + v.y * v.y;
  #pragma unroll
  for (int off = 32; off; off >>= 1) s += __shfl_xor(s, off, 64);
  if (lane == 0) c2[c] = s;

  H2U h0, h1, l0, l1;
  h0.h = (_Float16)v.x;  l0.h = (_Float16)(v.x - (float)h0.h);
  h1.h = (_Float16)v.y;  l1.h = (_Float16)(v.y - (float)h1.h);
  const int cb = c >> 7, cm = c & 127;
  const int kc = lane >> 4, q = (lane >> 2) & 3, j0 = (lane & 3) * 2;
  const size_t off = (((size_t)(cb * 4 + kc) * 4 + q) * 128 + cm) * 8 + j0;
  *(unsigned*)(Bh + off) = (unsigned)h0.u | ((unsigned)h1.u << 16);
  *(unsigned*)(Bl + off) = (unsigned)l0.u | ((unsigned)l1.u << 16);
}

// ---- main: 128 pts x 1024 centers per block; wave tile 64x64 (2x2 waves) ----
__global__ void __launch_bounds__(256)
__attribute__((amdgpu_waves_per_eu(2, 2)))
kmeans_mfma(
    const float* __restrict__ x,
    const u16* __restrict__ Bh_g, const u16* __restrict__ Bl_g,
    const float* __restrict__ c2g,
    float* __restrict__ out_cost, float* __restrict__ out_idx)
{
  __shared__ __align__(16) u16 Ah[16384];   // [kc4][q4][m128][j8]  32 KB
  __shared__ __align__(16) u16 Al[16384];   //                      32 KB
  __shared__ float redV[256];               //                       1 KB
  __shared__ int   redI[256];               //                       1 KB

  const int tid = threadIdx.x;
  const int wave = tid >> 6, lane = tid & 63;
  const int wr = wave >> 1, wc = wave & 1;    // wave row/col in 2x2
  const int q = lane >> 4, ln = lane & 15;
  const int m0 = blockIdx.x * MT;

  // ---- stage A tile: fp32 -> (hi,lo) f16, tiled layout ----
  #pragma unroll
  for (int i = 0; i < 16; ++i) {
    const int flat = i * 256 + tid;            // 4096 float4s = 128x128 floats
    const int m = flat >> 5, c4 = flat & 31, k0 = c4 * 4;
    const float4 v = *(const float4*)(x + (size_t)(m0 + m) * D + k0);
    const int kc = k0 >> 5, qq = (k0 >> 3) & 3, j0 = k0 & 7;
    const float vv[4] = {v.x, v.y, v.z, v.w};
    H2U h[4], l[4];
    #pragma unroll
    for (int z = 0; z < 4; ++z) {
      h[z].h = (_Float16)vv[z];
      l[z].h = (_Float16)(vv[z] - (float)h[z].h);
    }
    const int off = ((kc * 4 + qq) * 128 + m) * 8 + j0;
    uint2 hp, lp;
    hp.x = h[0].u | ((unsigned)h[1].u << 16); hp.y = h[2].u | ((unsigned)h[3].u << 16);
    lp.x = l[0].u | ((unsigned)l[1].u << 16); lp.y = l[2].u | ((unsigned)l[3].u << 16);
    *(uint2*)(Ah + off) = hp;
    *(uint2*)(Al + off) = lp;
  }
  __syncthreads();   // A is READ-ONLY from here on -- last barrier before epilogue

  // ---- x2 per point (thread tid<128 owns m=tid) ----
  float x2m = 0.f;
  if (tid < MT) {
    #pragma unroll
    for (int kq = 0; kq < 16; ++kq) {
      const f16x8 hv = *(const f16x8*)(Ah + (kq * 128 + tid) * 8);
      const f16x8 lv = *(const f16x8*)(Al + (kq * 128 + tid) * 8);
      #pragma unroll
      for (int e = 0; e < 8; ++e) {
        const float xv = (float)hv[e] + (float)lv[e];
        x2m += xv * xv;
      }
    }
  }

  // per-lane base into the fragment-major B arrays (u16 units)
  const size_t laneB = ((size_t)q * 128 + wc * 64 + ln) * 8;
  const u16* bhP = Bh_g + laneB;
  const u16* blP = Bl_g + laneB;

  float bestV[16]; int bestI[16];
  #pragma unroll
  for (int b = 0; b < 16; ++b) { bestV[b] = 3.4e38f; bestI[b] = 0; }

  // bh ping-pong: set parity = kc & 1 (statically unrolled kc)
  f16x8 bhS[2][4];
  #pragma unroll
  for (int t = 0; t < 4; ++t)            // chunk 0 -> set0
    bhS[0][t] = *(const f16x8*)(bhP + t * 128);

  for (int ct = 0; ct < 8; ++ct) {
    f32x4 acc[4][4];
    #pragma unroll
    for (int mt = 0; mt < 4; ++mt)
      #pragma unroll
      for (int nt = 0; nt < 4; ++nt)
        acc[mt][nt] = (f32x4){0.f, 0.f, 0.f, 0.f};

    // c2 for this ct tile (L2 hit, consumed a full tile-compute later)
    float c2v[4];
    #pragma unroll
    for (int nt = 0; nt < 4; ++nt)
      c2v[nt] = c2g[ct * 128 + wc * 64 + nt * 16 + ln];

    #pragma unroll
    for (int kc = 0; kc < 4; ++kc) {
      const int cc = ct * 4 + kc;
      const int cur = kc & 1, nxt = cur ^ 1;

      // just-in-time bl for THIS chunk (consumed in pass 3 -> latency
      // hides under passes 1-2); only 16 VGPRs in flight
      f16x8 bl[4];
      #pragma unroll
      for (int t = 0; t < 4; ++t)
        bl[t] = *(const f16x8*)(blP + (size_t)cc * 4096 + t * 128);

      // A fragments for chunk cc from (read-only) LDS
      f16x8 ah[4], al[4];
      #pragma unroll
      for (int t = 0; t < 4; ++t) {
        const int aoff = ((kc * 4 + q) * 128 + wr * 64 + t * 16 + ln) * 8;
        ah[t] = *(const f16x8*)(Ah + aoff);
        al[t] = *(const f16x8*)(Al + aoff);
      }

      // pass 1: ah . bh
      #pragma unroll
      for (int mt = 0; mt < 4; ++mt)
        #pragma unroll
        for (int nt = 0; nt < 4; ++nt)
          acc[mt][nt] = __builtin_amdgcn_mfma_f32_16x16x32_f16(ah[mt], bhS[cur][nt], acc[mt][nt], 0, 0, 0);

      // prefetch bh for chunk cc+1 (completes during passes 2-3)
      if (kc < 3 || ct < 7) {
        const size_t goff = (size_t)(cc + 1) * 4096;
        #pragma unroll
        for (int t = 0; t < 4; ++t)
          bhS[nxt][t] = *(const f16x8*)(bhP + goff + t * 128);
      }

      // pass 2: al . bh
      #pragma unroll
      for (int mt = 0; mt < 4; ++mt)
        #pragma unroll
        for (int nt = 0; nt < 4; ++nt)
          acc[mt][nt] = __builtin_amdgcn_mfma_f32_16x16x32_f16(al[mt], bhS[cur][nt], acc[mt][nt], 0, 0, 0);

      // pass 3: ah . bl
      #pragma unroll
      for (int mt = 0; mt < 4; ++mt)
        #pragma unroll
        for (int nt = 0; nt < 4; ++nt)
          acc[mt][nt] = __builtin_amdgcn_mfma_f32_16x16x32_f16(ah[mt], bl[nt], acc[mt][nt], 0, 0, 0);
    }

    // epilogue: s = c2 - 2*dot; running min (n strictly increasing per lane)
    #pragma unroll
    for (int nt = 0; nt < 4; ++nt) {
      const int n = ct * 128 + wc * 64 + nt * 16 + ln;
      #pragma unroll
      for (int mt = 0; mt < 4; ++mt)
        #pragma unroll
        for (int r = 0; r < 4; ++r) {
          const float s = __builtin_fmaf(-2.f, acc[mt][nt][r], c2v[nt]);
          const int b = mt * 4 + r;
          if (s < bestV[b]) { bestV[b] = s; bestI[b] = n; }
        }
    }
  }

  // ---- reduce across the 16 lanes (ln) sharing the same m rows ----
  #pragma unroll
  for (int b = 0; b < 16; ++b) {
    float v = bestV[b]; int idx = bestI[b];
    #pragma unroll
    for (int off = 1; off < 16; off <<= 1) {
      const float ov = __shfl_xor(v, off, 64);
      const int   oi = __shfl_xor(idx, off, 64);
      if (ov < v || (ov == v && oi < idx)) { v = ov; idx = oi; }
    }
    bestV[b] = v; bestI[b] = idx;
  }

  if (ln == 0) {
    #pragma unroll
    for (int b = 0; b < 16; ++b) {
      const int ml = wr * 64 + (b >> 2) * 16 + q * 4 + (b & 3);
      redV[ml * 2 + wc] = bestV[b];
      redI[ml * 2 + wc] = bestI[b];
    }
  }
  __syncthreads();
  if (tid < MT) {
    float v = redV[tid * 2]; int idx = redI[tid * 2];
    const float v1 = redV[tid * 2 + 1]; const int i1 = redI[tid * 2 + 1];
    if (v1 < v || (v1 == v && i1 < idx)) { v = v1; idx = i1; }
    float cost = x2m + v;
    if (cost < 0.f) cost = 0.f;          // clamp like reference
    out_cost[m0 + tid] = cost;
    out_idx[m0 + tid]  = (float)idx;
  }
}

extern "C" void kernel_launch(void* const* d_in, const int* in_sizes, int n_in,
                              void* d_out, int out_size, void* d_ws, size_t ws_size,
                              hipStream_t stream) {
  const float* x       = (const float*)d_in[0];
  const float* centers = (const float*)d_in[1];
  u16*   Bh = (u16*)d_ws;                    // 256 KB
  u16*   Bl = Bh + (size_t)K * D;            // 256 KB
  float* c2 = (float*)(Bl + (size_t)K * D);  // 4 KB
  float* out_cost = (float*)d_out;
  float* out_idx  = out_cost + N;

  prep_centers<<<K / 4, 256, 0, stream>>>(centers, Bh, Bl, c2);
  kmeans_mfma<<<N / MT, 256, 0, stream>>>(x, Bh, Bl, c2, out_cost, out_idx);
}